// Round 4
// baseline (853.275 us; speedup 1.0000x reference)
//
#include <hip/hip_runtime.h>
#include <hip/hip_bf16.h>

// N=50000 nodes, R=16 relations, H=64 hidden, L=32 labels, E=1.6M edges
// Pipeline (no float atomics, no divergent shuffles):
//   count_kernel: cnt[r*N+d] (verified int-atomic histogram)
//   prep_kernel:  invt[r,d]=1/cnt, deg[d]=sum_r cnt, start/cursor partition
//   scatter_kernel: esort[pos] = (rel<<20)|src, dst-grouped segments
//   layer1_gather4: wave per dst, 4 edges x 16 lanes x float4 w1 gather,
//                   converged shfl_xor combine, writes x = relu(agg+root1+bias1)
//   zgemm_kernel: z[n,r*32+l] = x[n,:] @ w2[r]  (bf16 output, 51 MB)
//   layer2_gather2: wave per dst, 2 edges/iter z gather + fused root2 matvec
//                   + bias + sigmoid, single write per (d,l)

__global__ void count_kernel(const int* __restrict__ dst, const int* __restrict__ et,
                             int* __restrict__ cnt, int E, int N) {
    int i = blockIdx.x * blockDim.x + threadIdx.x;
    int stride = gridDim.x * blockDim.x;
    for (; i < E; i += stride) atomicAdd(&cnt[et[i] * N + dst[i]], 1);
}

__global__ void prep_kernel(const int* __restrict__ cnt, float* __restrict__ invt,
                            int* __restrict__ deg, int* __restrict__ start,
                            int* __restrict__ cursor, int* __restrict__ counter,
                            int N, int R) {
    int d = blockIdx.x * blockDim.x + threadIdx.x;
    if (d < N) {
        int dg = 0;
        for (int r = 0; r < R; ++r) {
            int c = cnt[r * N + d];
            dg += c;
            invt[r * N + d] = (c > 0) ? 1.0f / (float)c : 0.0f;
        }
        deg[d] = dg;
        int s = atomicAdd(counter, dg);
        start[d] = s;
        cursor[d] = s;
    }
}

__global__ void scatter_kernel(const int* __restrict__ src, const int* __restrict__ dst,
                               const int* __restrict__ et, int* __restrict__ cursor,
                               int* __restrict__ esort, int E) {
    int i = blockIdx.x * blockDim.x + threadIdx.x;
    int stride = gridDim.x * blockDim.x;
    for (; i < E; i += stride) {
        int pos = atomicAdd(&cursor[dst[i]], 1);
        esort[pos] = (et[i] << 20) | src[i];   // rel (4b) | src (<2^20)
    }
}

// Wave per dst. lane = e4*16 + h4: e4 = edge slot (4 edges/iter), h4 = h-quad.
// All shuffles execute unconditionally (fully converged).
__global__ __launch_bounds__(256) void layer1_gather4(
        const int* __restrict__ esort, const int* __restrict__ start,
        const int* __restrict__ deg, const float* __restrict__ invt,
        const float* __restrict__ w1, const float* __restrict__ root1,
        const float* __restrict__ bias1, float* __restrict__ x, int N) {
    int lane = threadIdx.x & 63;
    int e4 = lane >> 4;       // 0..3
    int h4 = lane & 15;       // h = h4*4 .. h4*4+3
    int wave = (blockIdx.x * blockDim.x + threadIdx.x) >> 6;
    int nwaves = (gridDim.x * blockDim.x) >> 6;
    for (int d = wave; d < N; d += nwaves) {
        int beg = start[d];
        int dg = deg[d];
        float4 acc = make_float4(0.f, 0.f, 0.f, 0.f);
        for (int j = 0; j < dg; j += 4) {
            int e = j + e4;
            if (e < dg) {                       // loads only in divergent region
                int vj = esort[beg + e];
                int r = vj >> 20;
                int s = vj & 0xFFFFF;
                float inv = invt[r * N + d];
                const float4 w = *(const float4*)(w1 + ((size_t)r * N + s) * 64 + h4 * 4);
                acc.x += w.x * inv;
                acc.y += w.y * inv;
                acc.z += w.z * inv;
                acc.w += w.w * inv;
            }
        }
        // combine edge slots: xor 16 then xor 32 (converged, all sources active)
        acc.x += __shfl_xor(acc.x, 16, 64); acc.y += __shfl_xor(acc.y, 16, 64);
        acc.z += __shfl_xor(acc.z, 16, 64); acc.w += __shfl_xor(acc.w, 16, 64);
        acc.x += __shfl_xor(acc.x, 32, 64); acc.y += __shfl_xor(acc.y, 32, 64);
        acc.z += __shfl_xor(acc.z, 32, 64); acc.w += __shfl_xor(acc.w, 32, 64);
        if (e4 == 0) {
            float4 rt = *(const float4*)(root1 + (size_t)d * 64 + h4 * 4);
            float4 bs = *(const float4*)(bias1 + h4 * 4);
            float4 o;
            o.x = acc.x + rt.x + bs.x; o.x = o.x > 0.f ? o.x : 0.f;
            o.y = acc.y + rt.y + bs.y; o.y = o.y > 0.f ? o.y : 0.f;
            o.z = acc.z + rt.z + bs.z; o.z = o.z > 0.f ? o.z : 0.f;
            o.w = acc.w + rt.w + bs.w; o.w = o.w > 0.f ? o.w : 0.f;
            *(float4*)(x + (size_t)d * 64 + h4 * 4) = o;
        }
    }
}

// z[n, r*32+l] = sum_h x[n,h] * w2[r,h,l], stored bf16.
__global__ void zgemm_kernel(const float* __restrict__ x, const float* __restrict__ w2,
                             __hip_bfloat16* __restrict__ z, int N) {
    __shared__ float xs[64];
    int t = threadIdx.x;          // 256 threads; cols t and t+256 of 512
    int o0 = t, o1 = t + 256;
    float wc0[64], wc1[64];
    {
        const float* w0  = w2 + (size_t)(o0 >> 5) * 64 * 32 + (o0 & 31);
        const float* w1p = w2 + (size_t)(o1 >> 5) * 64 * 32 + (o1 & 31);
#pragma unroll
        for (int h = 0; h < 64; ++h) {
            wc0[h] = w0[h * 32];
            wc1[h] = w1p[h * 32];
        }
    }
    for (int n = blockIdx.x; n < N; n += gridDim.x) {
        __syncthreads();
        if (t < 64) xs[t] = x[(size_t)n * 64 + t];
        __syncthreads();
        float a0 = 0.0f, a1 = 0.0f;
#pragma unroll
        for (int h = 0; h < 64; ++h) {
            float xv = xs[h];
            a0 += xv * wc0[h];
            a1 += xv * wc1[h];
        }
        z[(size_t)n * 512 + o0] = __float2bfloat16(a0);
        z[(size_t)n * 512 + o1] = __float2bfloat16(a1);
    }
}

// Wave per dst; 2 edges per iter (sub = lane>>5), l = lane&31.
// out[d,l] = sigmoid( sum_e z[s_e,r_e,l]*invt[r_e,d] + x[d,:]@root2[:,l] + bias2[l] )
__global__ __launch_bounds__(256) void layer2_gather2(
        const int* __restrict__ esort, const int* __restrict__ start,
        const int* __restrict__ deg, const float* __restrict__ invt,
        const __hip_bfloat16* __restrict__ z, const float* __restrict__ x,
        const float* __restrict__ root2, const float* __restrict__ bias2,
        float* __restrict__ out, int N, int R) {
    int lane = threadIdx.x & 63;
    int sub = lane >> 5;
    int l = lane & 31;
    int wave = (blockIdx.x * blockDim.x + threadIdx.x) >> 6;
    int nwaves = (gridDim.x * blockDim.x) >> 6;
    for (int d = wave; d < N; d += nwaves) {
        int beg = start[d];
        int dg = deg[d];
        float acc = 0.0f;
        for (int j = 0; j < dg; j += 2) {
            int e = j + sub;
            if (e < dg) {                       // loads only; no shfl in here
                int vj = esort[beg + e];
                int r = vj >> 20;
                int s = vj & 0xFFFFF;
                acc += __bfloat162float(z[((size_t)s * R + r) * 32 + l]) * invt[r * N + d];
            }
        }
        acc += __shfl_xor(acc, 32, 64);         // converged
        float xr = x[(size_t)d * 64 + lane];
        float rt = 0.0f;
#pragma unroll
        for (int h = 0; h < 64; ++h) rt += __shfl(xr, h, 64) * root2[h * 32 + l];  // converged
        float logit = acc + rt + bias2[l];
        if (sub == 0) out[(size_t)d * 32 + l] = 1.0f / (1.0f + __expf(-logit));
    }
}

// ---------------- fallback path (small workspace): round-2 verified atomics ----
__global__ void layer1_kernel(const int* __restrict__ src, const int* __restrict__ dst,
                              const int* __restrict__ et, const int* __restrict__ cnt,
                              const float* __restrict__ w1, float* __restrict__ h1,
                              int E, int N) {
    int lane = threadIdx.x & 63;
    int wave = (blockIdx.x * blockDim.x + threadIdx.x) >> 6;
    int nwaves = (gridDim.x * blockDim.x) >> 6;
    for (int e = wave; e < E; e += nwaves) {
        int r = et[e], s = src[e], d = dst[e];
        float inv = 1.0f / (float)cnt[r * N + d];
        atomicAdd(&h1[(size_t)d * 64 + lane], w1[((size_t)r * N + s) * 64 + lane] * inv);
    }
}
__global__ void x_kernel(float* __restrict__ h1, const float* __restrict__ root1,
                         const float* __restrict__ bias1, int NH) {
    int i = blockIdx.x * blockDim.x + threadIdx.x;
    int stride = gridDim.x * blockDim.x;
    for (; i < NH; i += stride) {
        float v = h1[i] + root1[i] + bias1[i & 63];
        h1[i] = v > 0.0f ? v : 0.0f;
    }
}
__global__ void layer2_kernel(const int* __restrict__ src, const int* __restrict__ dst,
                              const int* __restrict__ et, const int* __restrict__ cnt,
                              const float* __restrict__ x, const float* __restrict__ w2,
                              float* __restrict__ out, int E, int N) {
    int lane = threadIdx.x & 63;
    int l = lane & 31;
    int half = lane >> 5;
    int wave = (blockIdx.x * blockDim.x + threadIdx.x) >> 6;
    int nwaves = (gridDim.x * blockDim.x) >> 6;
    for (int e = wave; e < E; e += nwaves) {
        int r = et[e], s = src[e], d = dst[e];
        float inv = 1.0f / (float)cnt[r * N + d];
        float xv = x[(size_t)s * 64 + lane];
        const float* w2r = w2 + ((size_t)r * 64 + half * 32) * 32 + l;
        float acc = 0.0f;
#pragma unroll
        for (int i2 = 0; i2 < 32; ++i2) acc += __shfl(xv, half * 32 + i2, 64) * w2r[(size_t)i2 * 32];
        acc += __shfl_xor(acc, 32, 64);
        if (half == 0) atomicAdd(&out[(size_t)d * 32 + l], acc * inv);
    }
}
__global__ void final_kernel(float* __restrict__ out, const float* __restrict__ x,
                             const float* __restrict__ root2, const float* __restrict__ bias2,
                             int N) {
    int idx = blockIdx.x * blockDim.x + threadIdx.x;
    int stride = gridDim.x * blockDim.x;
    int total = N * 32;
    for (; idx < total; idx += stride) {
        int n = idx >> 5, l = idx & 31;
        float acc = out[idx] + bias2[l];
        const float* xr = x + (size_t)n * 64;
#pragma unroll
        for (int h = 0; h < 64; ++h) acc += xr[h] * root2[h * 32 + l];
        out[idx] = 1.0f / (1.0f + __expf(-acc));
    }
}

extern "C" void kernel_launch(void* const* d_in, const int* in_sizes, int n_in,
                              void* d_out, int out_size, void* d_ws, size_t ws_size,
                              hipStream_t stream) {
    const int*   edge_index = (const int*)d_in[0];   // [2, E]
    const int*   edge_type  = (const int*)d_in[1];   // [E]
    const float* w1         = (const float*)d_in[2]; // [R, N, 64]
    const float* root1      = (const float*)d_in[3]; // [N, 64]
    const float* bias1      = (const float*)d_in[4]; // [64]
    const float* w2         = (const float*)d_in[5]; // [R, 64, 32]
    const float* root2      = (const float*)d_in[6]; // [64, 32]
    const float* bias2      = (const float*)d_in[7]; // [32]
    float* out = (float*)d_out;

    int E = in_sizes[1];
    int H = in_sizes[4];            // 64
    int L = in_sizes[7];            // 32
    int N = in_sizes[3] / H;
    int R = in_sizes[5] / (H * L);

    const int* src = edge_index;
    const int* dst = edge_index + E;

    // ws layout: [cnt R*N][counter 64B][invt R*N f32][deg N][start N][cursor N]
    //            [esort E][x N*H f32][z N*R*L bf16]   (~77 MB)
    size_t off_cnt     = 0;
    size_t off_counter = off_cnt + (size_t)R * N * 4;
    size_t off_invt    = off_counter + 64;
    size_t off_deg     = off_invt + (size_t)R * N * 4;
    size_t off_start   = off_deg + (size_t)N * 4;
    size_t off_cursor  = off_start + (size_t)N * 4;
    size_t off_esort   = off_cursor + (size_t)N * 4;
    size_t off_x       = off_esort + (size_t)E * 4;
    size_t off_z       = off_x + (size_t)N * H * 4;
    size_t need        = off_z + (size_t)N * R * L * 2;

    char* ws = (char*)d_ws;
    if (ws_size >= need) {
        int*   cnt     = (int*)(ws + off_cnt);
        int*   counter = (int*)(ws + off_counter);
        float* invt    = (float*)(ws + off_invt);
        int*   deg     = (int*)(ws + off_deg);
        int*   start   = (int*)(ws + off_start);
        int*   cursor  = (int*)(ws + off_cursor);
        int*   esort   = (int*)(ws + off_esort);
        float* x       = (float*)(ws + off_x);
        __hip_bfloat16* z = (__hip_bfloat16*)(ws + off_z);

        hipMemsetAsync(cnt, 0, (size_t)R * N * 4 + 64, stream);  // cnt + counter
        count_kernel  <<<2048, 256, 0, stream>>>(dst, edge_type, cnt, E, N);
        prep_kernel   <<<(N + 255) / 256, 256, 0, stream>>>(cnt, invt, deg, start, cursor, counter, N, R);
        scatter_kernel<<<2048, 256, 0, stream>>>(src, dst, edge_type, cursor, esort, E);
        layer1_gather4<<<(N + 3) / 4, 256, 0, stream>>>(esort, start, deg, invt, w1, root1, bias1, x, N);
        zgemm_kernel  <<<2048, 256, 0, stream>>>(x, w2, z, N);
        layer2_gather2<<<(N + 3) / 4, 256, 0, stream>>>(esort, start, deg, invt, z, x, root2, bias2, out, N, R);
    } else {
        // fallback: round-2 verified atomic path (needs ~16 MB)
        size_t cnt_bytes = (size_t)R * N * sizeof(int);
        int*   cnt = (int*)ws;
        float* h1  = (float*)(ws + cnt_bytes);
        hipMemsetAsync(cnt, 0, cnt_bytes + (size_t)N * H * sizeof(float), stream);
        hipMemsetAsync(out, 0, (size_t)N * L * sizeof(float), stream);
        count_kernel <<<2048, 256, 0, stream>>>(dst, edge_type, cnt, E, N);
        layer1_kernel<<<4096, 256, 0, stream>>>(src, dst, edge_type, cnt, w1, h1, E, N);
        x_kernel     <<<2048, 256, 0, stream>>>(h1, root1, bias1, N * H);
        layer2_kernel<<<4096, 256, 0, stream>>>(src, dst, edge_type, cnt, h1, w2, out, E, N);
        final_kernel <<<2048, 256, 0, stream>>>(out, h1, root2, bias2, N);
    }
}

// Round 5
// 462.408 us; speedup vs baseline: 1.8453x; 1.8453x over previous
//
#include <hip/hip_runtime.h>
#include <hip/hip_bf16.h>

// N=50000 nodes, R<=16 relations, H=64 hidden, L=32 labels, E=1.6M edges
// Gather pipeline, MLP-oriented:
//   count -> prep (invtT[d*16+r], deg, start) -> scatter (esort=(r<<20)|s)
//   layer1_gather: wave/dst, lane=h; 64-edge code chunks loaded clamped;
//                  8 independent w1-row loads per group; converged shfls only.
//   zgemm: z[n, r*32+l] = x[n,:] @ w2[r]  (bf16)
//   layer2_gather: wave/dst, lane=sub*32+l; 4 pair-loads (8 edges) per group;
//                  fused root2 matvec (split by sub) + bias + sigmoid.

__global__ void count_kernel(const int* __restrict__ dst, const int* __restrict__ et,
                             int* __restrict__ cnt, int E, int N) {
    int i = blockIdx.x * blockDim.x + threadIdx.x;
    int stride = gridDim.x * blockDim.x;
    for (; i < E; i += stride) atomicAdd(&cnt[et[i] * N + dst[i]], 1);
}

__global__ void prep_kernel(const int* __restrict__ cnt, float* __restrict__ invtT,
                            int* __restrict__ deg, int* __restrict__ start,
                            int* __restrict__ cursor, int* __restrict__ counter,
                            int N, int R) {
    int d = blockIdx.x * blockDim.x + threadIdx.x;
    if (d < N) {
        int dg = 0;
        for (int r = 0; r < R; ++r) {
            int c = cnt[r * N + d];
            dg += c;
            invtT[d * 16 + r] = (c > 0) ? 1.0f / (float)c : 0.0f;
        }
        for (int r = R; r < 16; ++r) invtT[d * 16 + r] = 0.0f;
        deg[d] = dg;
        int s = atomicAdd(counter, dg);
        start[d] = s;
        cursor[d] = s;
    }
}

__global__ void scatter_kernel(const int* __restrict__ src, const int* __restrict__ dst,
                               const int* __restrict__ et, int* __restrict__ cursor,
                               int* __restrict__ esort, int E) {
    int i = blockIdx.x * blockDim.x + threadIdx.x;
    int stride = gridDim.x * blockDim.x;
    for (; i < E; i += stride) {
        int pos = atomicAdd(&cursor[dst[i]], 1);
        esort[pos] = (et[i] << 20) | src[i];   // rel (4b) | src (<2^20)
    }
}

// Wave per dst, lane = h. All shuffles converged (uniform loop bounds,
// clamped loads + multiplicative masks instead of divergent branches).
__global__ __launch_bounds__(256) void layer1_gather(
        const int* __restrict__ esort, const int* __restrict__ start,
        const int* __restrict__ deg, const float* __restrict__ invtT,
        const float* __restrict__ w1, const float* __restrict__ root1,
        const float* __restrict__ bias1, float* __restrict__ x, int N) {
    int lane = threadIdx.x & 63;
    int wave = (blockIdx.x * blockDim.x + threadIdx.x) >> 6;
    int nwaves = (gridDim.x * blockDim.x) >> 6;
    for (int d = wave; d < N; d += nwaves) {
        int beg = start[d];
        int dg = deg[d];
        float invc = invtT[d * 16 + (lane & 15)];   // lane r holds 1/cnt[r,d]
        float acc0 = 0.f, acc1 = 0.f, acc2 = 0.f, acc3 = 0.f;
        float acc4 = 0.f, acc5 = 0.f, acc6 = 0.f, acc7 = 0.f;
        for (int i = 0; i < dg; i += 64) {
            int v = esort[beg + min(i + lane, dg - 1)];   // coalesced, no branch
            int lim = min(64, dg - i);                    // wave-uniform
            for (int j = 0; j < lim; j += 8) {
                int c0 = __shfl(v, min(j + 0, lim - 1), 64);
                int c1 = __shfl(v, min(j + 1, lim - 1), 64);
                int c2 = __shfl(v, min(j + 2, lim - 1), 64);
                int c3 = __shfl(v, min(j + 3, lim - 1), 64);
                int c4 = __shfl(v, min(j + 4, lim - 1), 64);
                int c5 = __shfl(v, min(j + 5, lim - 1), 64);
                int c6 = __shfl(v, min(j + 6, lim - 1), 64);
                int c7 = __shfl(v, min(j + 7, lim - 1), 64);
                // 8 independent 256B row loads (uniform addresses per wave)
                float w0 = w1[((size_t)(c0 >> 20) * N + (c0 & 0xFFFFF)) * 64 + lane];
                float w1v = w1[((size_t)(c1 >> 20) * N + (c1 & 0xFFFFF)) * 64 + lane];
                float w2v = w1[((size_t)(c2 >> 20) * N + (c2 & 0xFFFFF)) * 64 + lane];
                float w3 = w1[((size_t)(c3 >> 20) * N + (c3 & 0xFFFFF)) * 64 + lane];
                float w4 = w1[((size_t)(c4 >> 20) * N + (c4 & 0xFFFFF)) * 64 + lane];
                float w5 = w1[((size_t)(c5 >> 20) * N + (c5 & 0xFFFFF)) * 64 + lane];
                float w6 = w1[((size_t)(c6 >> 20) * N + (c6 & 0xFFFFF)) * 64 + lane];
                float w7 = w1[((size_t)(c7 >> 20) * N + (c7 & 0xFFFFF)) * 64 + lane];
                // per-edge scale: shfl executes unconditionally; mask by multiply
                float f0 = __shfl(invc, c0 >> 20, 64) * ((j + 0 < lim) ? 1.f : 0.f);
                float f1 = __shfl(invc, c1 >> 20, 64) * ((j + 1 < lim) ? 1.f : 0.f);
                float f2 = __shfl(invc, c2 >> 20, 64) * ((j + 2 < lim) ? 1.f : 0.f);
                float f3 = __shfl(invc, c3 >> 20, 64) * ((j + 3 < lim) ? 1.f : 0.f);
                float f4 = __shfl(invc, c4 >> 20, 64) * ((j + 4 < lim) ? 1.f : 0.f);
                float f5 = __shfl(invc, c5 >> 20, 64) * ((j + 5 < lim) ? 1.f : 0.f);
                float f6 = __shfl(invc, c6 >> 20, 64) * ((j + 6 < lim) ? 1.f : 0.f);
                float f7 = __shfl(invc, c7 >> 20, 64) * ((j + 7 < lim) ? 1.f : 0.f);
                acc0 += w0 * f0;  acc1 += w1v * f1;
                acc2 += w2v * f2; acc3 += w3 * f3;
                acc4 += w4 * f4;  acc5 += w5 * f5;
                acc6 += w6 * f6;  acc7 += w7 * f7;
            }
        }
        float acc = ((acc0 + acc1) + (acc2 + acc3)) + ((acc4 + acc5) + (acc6 + acc7));
        float val = acc + root1[(size_t)d * 64 + lane] + bias1[lane];
        x[(size_t)d * 64 + lane] = val > 0.f ? val : 0.f;
    }
}

// z[n, r*32+l] = sum_h x[n,h] * w2[r,h,l], stored bf16.
__global__ void zgemm_kernel(const float* __restrict__ x, const float* __restrict__ w2,
                             __hip_bfloat16* __restrict__ z, int N) {
    __shared__ float xs[64];
    int t = threadIdx.x;          // 256 threads; cols t and t+256 of 512
    int o0 = t, o1 = t + 256;
    float wc0[64], wc1[64];
    {
        const float* w0  = w2 + (size_t)(o0 >> 5) * 64 * 32 + (o0 & 31);
        const float* w1p = w2 + (size_t)(o1 >> 5) * 64 * 32 + (o1 & 31);
#pragma unroll
        for (int h = 0; h < 64; ++h) {
            wc0[h] = w0[h * 32];
            wc1[h] = w1p[h * 32];
        }
    }
    for (int n = blockIdx.x; n < N; n += gridDim.x) {
        __syncthreads();
        if (t < 64) xs[t] = x[(size_t)n * 64 + t];
        __syncthreads();
        float a0 = 0.0f, a1 = 0.0f;
#pragma unroll
        for (int h = 0; h < 64; ++h) {
            float xv = xs[h];
            a0 += xv * wc0[h];
            a1 += xv * wc1[h];
        }
        z[(size_t)n * 512 + o0] = __float2bfloat16(a0);
        z[(size_t)n * 512 + o1] = __float2bfloat16(a1);
    }
}

// Wave per dst; lane = sub*32 + l. 4 edge-pairs (8 edges) in flight per group.
__global__ __launch_bounds__(256) void layer2_gather(
        const int* __restrict__ esort, const int* __restrict__ start,
        const int* __restrict__ deg, const float* __restrict__ invtT,
        const __hip_bfloat16* __restrict__ z, const float* __restrict__ x,
        const float* __restrict__ root2, const float* __restrict__ bias2,
        float* __restrict__ out, int N) {
    int lane = threadIdx.x & 63;
    int sub = lane >> 5;
    int l = lane & 31;
    int wave = (blockIdx.x * blockDim.x + threadIdx.x) >> 6;
    int nwaves = (gridDim.x * blockDim.x) >> 6;
    for (int d = wave; d < N; d += nwaves) {
        int beg = start[d];
        int dg = deg[d];
        float invc = invtT[d * 16 + (lane & 15)];
        float xr = x[(size_t)d * 64 + lane];
        float acc0 = 0.f, acc1 = 0.f, acc2 = 0.f, acc3 = 0.f;
        for (int i = 0; i < dg; i += 64) {
            int v = esort[beg + min(i + lane, dg - 1)];
            int lim = min(64, dg - i);                    // wave-uniform
            for (int j = 0; j < lim; j += 8) {
                // pair k covers edges j+2k+sub (per-lane index; shfl converged)
                int c0 = __shfl(v, min(j + 0 + sub, lim - 1), 64);
                int c1 = __shfl(v, min(j + 2 + sub, lim - 1), 64);
                int c2 = __shfl(v, min(j + 4 + sub, lim - 1), 64);
                int c3 = __shfl(v, min(j + 6 + sub, lim - 1), 64);
                float z0 = __bfloat162float(z[((size_t)(c0 & 0xFFFFF) * 16 + (c0 >> 20)) * 32 + l]);
                float z1 = __bfloat162float(z[((size_t)(c1 & 0xFFFFF) * 16 + (c1 >> 20)) * 32 + l]);
                float z2 = __bfloat162float(z[((size_t)(c2 & 0xFFFFF) * 16 + (c2 >> 20)) * 32 + l]);
                float z3 = __bfloat162float(z[((size_t)(c3 & 0xFFFFF) * 16 + (c3 >> 20)) * 32 + l]);
                // masks are per-lane (sub): multiplicative select, no branch
                float f0 = __shfl(invc, c0 >> 20, 64) * ((j + 0 + sub < lim) ? 1.f : 0.f);
                float f1 = __shfl(invc, c1 >> 20, 64) * ((j + 2 + sub < lim) ? 1.f : 0.f);
                float f2 = __shfl(invc, c2 >> 20, 64) * ((j + 4 + sub < lim) ? 1.f : 0.f);
                float f3 = __shfl(invc, c3 >> 20, 64) * ((j + 6 + sub < lim) ? 1.f : 0.f);
                acc0 += z0 * f0;
                acc1 += z1 * f1;
                acc2 += z2 * f2;
                acc3 += z3 * f3;
            }
        }
        float acc = (acc0 + acc1) + (acc2 + acc3);
        // root2 matvec split across sub halves (h = sub*32 + h2)
        float rt = 0.f;
#pragma unroll
        for (int h2 = 0; h2 < 32; ++h2) {
            int h = sub * 32 + h2;
            rt += __shfl(xr, h, 64) * root2[h * 32 + l];
        }
        float tot = acc + rt;
        tot += __shfl_xor(tot, 32, 64);               // combine sub halves
        float logit = tot + bias2[l];
        if (sub == 0) out[(size_t)d * 32 + l] = 1.0f / (1.0f + __expf(-logit));
    }
}

// ---------------- fallback path (small workspace): round-2 verified atomics ----
__global__ void layer1_kernel(const int* __restrict__ src, const int* __restrict__ dst,
                              const int* __restrict__ et, const int* __restrict__ cnt,
                              const float* __restrict__ w1, float* __restrict__ h1,
                              int E, int N) {
    int lane = threadIdx.x & 63;
    int wave = (blockIdx.x * blockDim.x + threadIdx.x) >> 6;
    int nwaves = (gridDim.x * blockDim.x) >> 6;
    for (int e = wave; e < E; e += nwaves) {
        int r = et[e], s = src[e], d = dst[e];
        float inv = 1.0f / (float)cnt[r * N + d];
        atomicAdd(&h1[(size_t)d * 64 + lane], w1[((size_t)r * N + s) * 64 + lane] * inv);
    }
}
__global__ void x_kernel(float* __restrict__ h1, const float* __restrict__ root1,
                         const float* __restrict__ bias1, int NH) {
    int i = blockIdx.x * blockDim.x + threadIdx.x;
    int stride = gridDim.x * blockDim.x;
    for (; i < NH; i += stride) {
        float v = h1[i] + root1[i] + bias1[i & 63];
        h1[i] = v > 0.0f ? v : 0.0f;
    }
}
__global__ void layer2_kernel(const int* __restrict__ src, const int* __restrict__ dst,
                              const int* __restrict__ et, const int* __restrict__ cnt,
                              const float* __restrict__ x, const float* __restrict__ w2,
                              float* __restrict__ out, int E, int N) {
    int lane = threadIdx.x & 63;
    int l = lane & 31;
    int half = lane >> 5;
    int wave = (blockIdx.x * blockDim.x + threadIdx.x) >> 6;
    int nwaves = (gridDim.x * blockDim.x) >> 6;
    for (int e = wave; e < E; e += nwaves) {
        int r = et[e], s = src[e], d = dst[e];
        float inv = 1.0f / (float)cnt[r * N + d];
        float xv = x[(size_t)s * 64 + lane];
        const float* w2r = w2 + ((size_t)r * 64 + half * 32) * 32 + l;
        float acc = 0.0f;
#pragma unroll
        for (int i2 = 0; i2 < 32; ++i2) acc += __shfl(xv, half * 32 + i2, 64) * w2r[(size_t)i2 * 32];
        acc += __shfl_xor(acc, 32, 64);
        if (half == 0) atomicAdd(&out[(size_t)d * 32 + l], acc * inv);
    }
}
__global__ void final_kernel(float* __restrict__ out, const float* __restrict__ x,
                             const float* __restrict__ root2, const float* __restrict__ bias2,
                             int N) {
    int idx = blockIdx.x * blockDim.x + threadIdx.x;
    int stride = gridDim.x * blockDim.x;
    int total = N * 32;
    for (; idx < total; idx += stride) {
        int n = idx >> 5, l = idx & 31;
        float acc = out[idx] + bias2[l];
        const float* xr = x + (size_t)n * 64;
#pragma unroll
        for (int h = 0; h < 64; ++h) acc += xr[h] * root2[h * 32 + l];
        out[idx] = 1.0f / (1.0f + __expf(-acc));
    }
}

extern "C" void kernel_launch(void* const* d_in, const int* in_sizes, int n_in,
                              void* d_out, int out_size, void* d_ws, size_t ws_size,
                              hipStream_t stream) {
    const int*   edge_index = (const int*)d_in[0];   // [2, E]
    const int*   edge_type  = (const int*)d_in[1];   // [E]
    const float* w1         = (const float*)d_in[2]; // [R, N, 64]
    const float* root1      = (const float*)d_in[3]; // [N, 64]
    const float* bias1      = (const float*)d_in[4]; // [64]
    const float* w2         = (const float*)d_in[5]; // [R, 64, 32]
    const float* root2      = (const float*)d_in[6]; // [64, 32]
    const float* bias2      = (const float*)d_in[7]; // [32]
    float* out = (float*)d_out;

    int E = in_sizes[1];
    int H = in_sizes[4];            // 64
    int L = in_sizes[7];            // 32
    int N = in_sizes[3] / H;
    int R = in_sizes[5] / (H * L);  // <= 16

    const int* src = edge_index;
    const int* dst = edge_index + E;

    // ws layout: [cnt R*N][counter 64B][invtT N*16 f32][deg N][start N][cursor N]
    //            [esort E][x N*H f32][z N*16*L bf16]
    size_t off_cnt     = 0;
    size_t off_counter = off_cnt + (size_t)R * N * 4;
    size_t off_invt    = off_counter + 64;
    size_t off_deg     = off_invt + (size_t)N * 16 * 4;
    size_t off_start   = off_deg + (size_t)N * 4;
    size_t off_cursor  = off_start + (size_t)N * 4;
    size_t off_esort   = off_cursor + (size_t)N * 4;
    size_t off_x       = off_esort + (size_t)E * 4;
    size_t off_z       = off_x + (size_t)N * H * 4;
    size_t need        = off_z + (size_t)N * 16 * L * 2;

    char* ws = (char*)d_ws;
    if (ws_size >= need && R <= 16) {
        int*   cnt     = (int*)(ws + off_cnt);
        int*   counter = (int*)(ws + off_counter);
        float* invtT   = (float*)(ws + off_invt);
        int*   deg     = (int*)(ws + off_deg);
        int*   start   = (int*)(ws + off_start);
        int*   cursor  = (int*)(ws + off_cursor);
        int*   esort   = (int*)(ws + off_esort);
        float* x       = (float*)(ws + off_x);
        __hip_bfloat16* z = (__hip_bfloat16*)(ws + off_z);

        hipMemsetAsync(cnt, 0, (size_t)R * N * 4 + 64, stream);  // cnt + counter
        count_kernel  <<<2048, 256, 0, stream>>>(dst, edge_type, cnt, E, N);
        prep_kernel   <<<(N + 255) / 256, 256, 0, stream>>>(cnt, invtT, deg, start, cursor, counter, N, R);
        scatter_kernel<<<2048, 256, 0, stream>>>(src, dst, edge_type, cursor, esort, E);
        layer1_gather <<<(N + 3) / 4, 256, 0, stream>>>(esort, start, deg, invtT, w1, root1, bias1, x, N);
        zgemm_kernel  <<<2048, 256, 0, stream>>>(x, w2, z, N);
        layer2_gather <<<(N + 3) / 4, 256, 0, stream>>>(esort, start, deg, invtT, z, x, root2, bias2, out, N);
    } else {
        // fallback: round-2 verified atomic path (needs ~16 MB)
        size_t cnt_bytes = (size_t)R * N * sizeof(int);
        int*   cnt = (int*)ws;
        float* h1  = (float*)(ws + cnt_bytes);
        hipMemsetAsync(cnt, 0, cnt_bytes + (size_t)N * H * sizeof(float), stream);
        hipMemsetAsync(out, 0, (size_t)N * L * sizeof(float), stream);
        count_kernel <<<2048, 256, 0, stream>>>(dst, edge_type, cnt, E, N);
        layer1_kernel<<<4096, 256, 0, stream>>>(src, dst, edge_type, cnt, w1, h1, E, N);
        x_kernel     <<<2048, 256, 0, stream>>>(h1, root1, bias1, N * H);
        layer2_kernel<<<4096, 256, 0, stream>>>(src, dst, edge_type, cnt, h1, w2, out, E, N);
        final_kernel <<<2048, 256, 0, stream>>>(out, h1, root2, bias2, N);
    }
}